// Round 16
// baseline (786.709 us; speedup 1.0000x reference)
//
#include <hip/hip_runtime.h>

typedef unsigned int uint;
typedef unsigned short ushort;
typedef short bf16x8 __attribute__((ext_vector_type(8)));
typedef float f32x4  __attribute__((ext_vector_type(4)));

// ---------------------------------------------------------------------------
// GNN scorer, round 16 (= round 15 + barrier-free proj):
//   sort: counting-sort by dst -> srcp (sorted), perm (sorted->orig), rowp.
//   proj_fused: bf16 MFMA over sorted edges; PER-LANE direct A loads in MFMA
//     fragment layout (no LDS A-tile, no main-loop barriers), G4 uint2 stores.
//   agg_csr: per-node CSR reduction over G4 (layers 1,2).
//   fused_apply_pre: apply_l GEMM + next layer's pre-GEMM in one kernel.
//   agg_apply3: layer-3 CSR reduction + apply3 + rowsum fused -> node_sum.
//   VM tower folded; sigmoid scores.
// G4 layout: ushort index = (pos>>2)*(GS*4) + col*4 + (pos&3).
// ---------------------------------------------------------------------------

__device__ __forceinline__ ushort f2bf(float f) {
    uint u = __float_as_uint(f);
    u += 0x7FFFu + ((u >> 16) & 1u);          // RNE
    return (ushort)(u >> 16);
}
__device__ __forceinline__ uint cvtpk(float lo, float hi) {
    uint r;
    asm("v_cvt_pk_bf16_f32 %0, %1, %2" : "=v"(r) : "v"(lo), "v"(hi));
    return r;
}
// pack 8 f32 (two float4) -> bf16x8 via 4 cvt_pk (RNE matches f2bf)
__device__ __forceinline__ bf16x8 pack_bf8(const float4& a, const float4& b) {
    uint u0 = cvtpk(a.x, a.y), u1 = cvtpk(a.z, a.w);
    uint u2 = cvtpk(b.x, b.y), u3 = cvtpk(b.z, b.w);
    uint4 q = {u0, u1, u2, u3};
    return *reinterpret_cast<bf16x8*>(&q);
}

// ---------------- node-side tiled GEMM (MODE 0=store, 1=relu+store)
template<int K0, int KP0, int K1, int KP1, int KC, int OUT, int WOUT,
         int NTC, int RPT, int MODE>
__global__ __launch_bounds__(256) void tile_gemm(
    const float* __restrict__ X0, int sx0,
    const float* __restrict__ X1, int sx1,
    const float* __restrict__ Wg, const float* __restrict__ Bg,
    float* __restrict__ Y, int sy, int nR)
{
    constexpr int KPT  = KP0 + KP1;
    constexpr int C4   = KC / 4;
    constexpr int OUTP = 4 * NTC;
    constexpr int NTR  = 256 / NTC;
    constexpr int TR   = NTR * RPT;
    static_assert(TR == 128, "tile must be 128 rows");
    static_assert(KPT % KC == 0, "KC must divide KPT");

    __shared__ float4 Xl[TR * C4];
    __shared__ float4 Wl[KC * NTC];
    __shared__ float  __align__(16) bl[OUTP];

    const int tid = threadIdx.x;
    const int r0  = blockIdx.x * TR;

    for (int idx = tid; idx < OUTP; idx += 256)
        bl[idx] = (Bg != nullptr && idx < OUT) ? Bg[idx] : 0.f;

    const int tc  = tid & (NTC - 1);
    const int tr  = tid / NTC;
    const int key = (RPT * tr) >> 3;

    float4 acc[RPT];
    #pragma unroll
    for (int i = 0; i < RPT; i++) acc[i] = make_float4(0.f, 0.f, 0.f, 0.f);

    for (int kc0 = 0; kc0 < KPT; kc0 += KC) {
        if (kc0 != 0) __syncthreads();
        for (int idx = tid; idx < TR * C4; idx += 256) {
            int r = idx / C4, c = idx - r * C4;
            int col = kc0 + 4 * c;
            int gr = r0 + r;
            float4 v = make_float4(0.f, 0.f, 0.f, 0.f);
            if (gr < nR) {
                if (KP1 == 0 || col < KP0)
                    v = *reinterpret_cast<const float4*>(X0 + (long long)gr * sx0 + col);
                else
                    v = *reinterpret_cast<const float4*>(X1 + (long long)gr * sx1 + (col - KP0));
            }
            int cs = c + ((r >> 3) % C4); if (cs >= C4) cs -= C4;
            Xl[r * C4 + cs] = v;
        }
        for (int idx = tid; idx < KC * OUTP; idx += 256) {
            int kl = idx / OUTP, o = idx - kl * OUTP;
            int k = kc0 + kl;
            float v = 0.f;
            if (o < OUT) {
                if (k < KP0) { if (k < K0) v = Wg[k * OUT + o]; }
                else { int kk = k - KP0; if (kk < K1) v = Wg[(K0 + kk) * OUT + o]; }
            }
            ((float*)Wl)[kl * OUTP + o] = v;
        }
        __syncthreads();

        const int km = key % C4;
        #pragma unroll 4
        for (int k4 = 0; k4 < C4; k4++) {
            int cs = k4 + km; if (cs >= C4) cs -= C4;
            float4 x[RPT];
            #pragma unroll
            for (int i = 0; i < RPT; i++)
                x[i] = Xl[(RPT * tr + i) * C4 + cs];
            #pragma unroll
            for (int kk = 0; kk < 4; kk++) {
                float4 w = Wl[(4 * k4 + kk) * NTC + tc];
                #pragma unroll
                for (int i = 0; i < RPT; i++) {
                    float xs = (kk == 0) ? x[i].x : (kk == 1) ? x[i].y
                             : (kk == 2) ? x[i].z : x[i].w;
                    acc[i].x = fmaf(xs, w.x, acc[i].x);
                    acc[i].y = fmaf(xs, w.y, acc[i].y);
                    acc[i].z = fmaf(xs, w.z, acc[i].z);
                    acc[i].w = fmaf(xs, w.w, acc[i].w);
                }
            }
        }
    }

    const float4 b4 = reinterpret_cast<float4*>(bl)[tc];
    const int o = 4 * tc;

    if (o < WOUT) {
        #pragma unroll
        for (int i = 0; i < RPT; i++) {
            int gr = r0 + RPT * tr + i;
            if (gr < nR) {
                float4 v;
                v.x = acc[i].x + b4.x; v.y = acc[i].y + b4.y;
                v.z = acc[i].z + b4.z; v.w = acc[i].w + b4.w;
                if (MODE == 1) {
                    v.x = fmaxf(v.x, 0.f); v.y = fmaxf(v.y, 0.f);
                    v.z = fmaxf(v.z, 0.f); v.w = fmaxf(v.w, 0.f);
                }
                *reinterpret_cast<float4*>(Y + (long long)gr * sy + o) = v;
            }
        }
    }
}

// ---------------- fused apply_l + pre-GEMM_{l+1}
template<int K0, int KP0, int K1, int KP1, int KC, int OUT1, int WOUT1,
         int OUT1P, int SY1, int OUT2, int OUT2P, int SY2,
         int NTC, int RPT, int NTC2, int RPT2>
__global__ __launch_bounds__(256) void fused_apply_pre(
    const float* __restrict__ X0, int sx0,
    const float* __restrict__ X1, int sx1,
    const float* __restrict__ Wa, const float* __restrict__ ba,
    const float* __restrict__ Wm, const float* __restrict__ bm,
    float* __restrict__ Y1, float* __restrict__ Y2, int nR)
{
    constexpr int KPT  = KP0 + KP1;
    constexpr int C4   = KC / 4;
    constexpr int OUTP = 4 * NTC;
    constexpr int NTR  = 256 / NTC;
    constexpr int TR   = NTR * RPT;
    constexpr int BLSZ = (OUTP > OUT2P) ? OUTP : OUT2P;
    static_assert(TR == 128, "tile must be 128 rows");
    static_assert(KPT % KC == 0, "KC must divide KPT");
    static_assert((256 / NTC2) * RPT2 == 128, "phase2 covers 128 rows");
    static_assert(OUT2P == 4 * NTC2, "phase2 col tiling");
    static_assert(128 * OUT1P <= TR * C4 * 4, "Hl fits in Xl");
    static_assert(OUT1 * OUT2P <= KC * NTC * 4, "Wm fits in Wl");

    __shared__ float4 Xl[TR * C4];
    __shared__ float4 Wl[KC * NTC];
    __shared__ float  __align__(16) bl[BLSZ];
    float* Hl = (float*)Xl;           // aliased: valid only after phase-1 K-loop

    const int tid = threadIdx.x;
    const int r0  = blockIdx.x * TR;

    for (int idx = tid; idx < OUTP; idx += 256)
        bl[idx] = (idx < OUT1) ? ba[idx] : 0.f;

    const int tc  = tid & (NTC - 1);
    const int tr  = tid / NTC;
    const int key = (RPT * tr) >> 3;

    float4 acc[RPT];
    #pragma unroll
    for (int i = 0; i < RPT; i++) acc[i] = make_float4(0.f, 0.f, 0.f, 0.f);

    for (int kc0 = 0; kc0 < KPT; kc0 += KC) {
        if (kc0 != 0) __syncthreads();
        for (int idx = tid; idx < TR * C4; idx += 256) {
            int r = idx / C4, c = idx - r * C4;
            int col = kc0 + 4 * c;
            int gr = r0 + r;
            float4 v = make_float4(0.f, 0.f, 0.f, 0.f);
            if (gr < nR) {
                if (KP1 == 0 || col < KP0)
                    v = *reinterpret_cast<const float4*>(X0 + (long long)gr * sx0 + col);
                else
                    v = *reinterpret_cast<const float4*>(X1 + (long long)gr * sx1 + (col - KP0));
            }
            int cs = c + ((r >> 3) % C4); if (cs >= C4) cs -= C4;
            Xl[r * C4 + cs] = v;
        }
        for (int idx = tid; idx < KC * OUTP; idx += 256) {
            int kl = idx / OUTP, o = idx - kl * OUTP;
            int k = kc0 + kl;
            float v = 0.f;
            if (o < OUT1) {
                if (k < KP0) { if (k < K0) v = Wa[k * OUT1 + o]; }
                else { int kk = k - KP0; if (kk < K1) v = Wa[(K0 + kk) * OUT1 + o]; }
            }
            ((float*)Wl)[kl * OUTP + o] = v;
        }
        __syncthreads();

        const int km = key % C4;
        #pragma unroll 4
        for (int k4 = 0; k4 < C4; k4++) {
            int cs = k4 + km; if (cs >= C4) cs -= C4;
            float4 x[RPT];
            #pragma unroll
            for (int i = 0; i < RPT; i++)
                x[i] = Xl[(RPT * tr + i) * C4 + cs];
            #pragma unroll
            for (int kk = 0; kk < 4; kk++) {
                float4 w = Wl[(4 * k4 + kk) * NTC + tc];
                #pragma unroll
                for (int i = 0; i < RPT; i++) {
                    float xs = (kk == 0) ? x[i].x : (kk == 1) ? x[i].y
                             : (kk == 2) ? x[i].z : x[i].w;
                    acc[i].x = fmaf(xs, w.x, acc[i].x);
                    acc[i].y = fmaf(xs, w.y, acc[i].y);
                    acc[i].z = fmaf(xs, w.z, acc[i].z);
                    acc[i].w = fmaf(xs, w.w, acc[i].w);
                }
            }
        }
    }

    const float4 b4 = reinterpret_cast<float4*>(bl)[tc];
    const int o = 4 * tc;

    __syncthreads();   // Xl/Wl/bl free: K-loop and bias read done block-wide

    // phase-1 epilogue: relu, global store, Hl stash (zeros for OOB rows)
    if (o < WOUT1) {
        #pragma unroll
        for (int i = 0; i < RPT; i++) {
            int lr = RPT * tr + i;
            int gr = r0 + lr;
            float4 v;
            v.x = fmaxf(acc[i].x + b4.x, 0.f); v.y = fmaxf(acc[i].y + b4.y, 0.f);
            v.z = fmaxf(acc[i].z + b4.z, 0.f); v.w = fmaxf(acc[i].w + b4.w, 0.f);
            if (gr >= nR) v = make_float4(0.f, 0.f, 0.f, 0.f);
            if (o < OUT1P)
                *reinterpret_cast<float4*>(Hl + lr * OUT1P + o) = v;
            if (gr < nR)
                *reinterpret_cast<float4*>(Y1 + (long long)gr * SY1 + o) = v;
        }
    }
    // stage phase-2 W (zero-padded cols) + bias into Wl/bl regions
    for (int idx = tid; idx < OUT1 * OUT2P; idx += 256) {
        int k = idx / OUT2P, oc = idx - k * OUT2P;
        ((float*)Wl)[idx] = (oc < OUT2) ? Wm[k * OUT2 + oc] : 0.f;
    }
    for (int idx = tid; idx < OUT2P; idx += 256)
        bl[idx] = (idx < OUT2) ? bm[idx] : 0.f;
    __syncthreads();

    // phase 2: P = h @ Wm + bm
    const int tc2 = tid & (NTC2 - 1);
    const int tr2 = tid / NTC2;
    float4 acc2[RPT2];
    #pragma unroll
    for (int i = 0; i < RPT2; i++) acc2[i] = make_float4(0.f, 0.f, 0.f, 0.f);

    #pragma unroll 4
    for (int k = 0; k < OUT1; k++) {
        float4 w = reinterpret_cast<float4*>((float*)Wl)[k * NTC2 + tc2];
        #pragma unroll
        for (int i = 0; i < RPT2; i++) {
            float xs = Hl[(RPT2 * tr2 + i) * OUT1P + k];
            acc2[i].x = fmaf(xs, w.x, acc2[i].x);
            acc2[i].y = fmaf(xs, w.y, acc2[i].y);
            acc2[i].z = fmaf(xs, w.z, acc2[i].z);
            acc2[i].w = fmaf(xs, w.w, acc2[i].w);
        }
    }
    const float4 b2 = reinterpret_cast<float4*>(bl)[tc2];
    #pragma unroll
    for (int i = 0; i < RPT2; i++) {
        int gr = r0 + RPT2 * tr2 + i;
        if (gr < nR) {
            float4 v;
            v.x = acc2[i].x + b2.x; v.y = acc2[i].y + b2.y;
            v.z = acc2[i].z + b2.z; v.w = acc2[i].w + b2.w;
            *reinterpret_cast<float4*>(Y2 + (long long)gr * SY2 + 4 * tc2) = v;
        }
    }
}

// ---------------- proj_fused: barrier-free, per-lane direct A loads.
// A frag layout (16x16x32 bf16): lane l holds row (l&15), k = (l>>4)*8+j,
// ks selects K-half (cols +ks*32). Wave wv owns rows wv*16..+15 of the tile.
__global__ __launch_bounds__(256) void proj_fused(
    const float* __restrict__ ef,
    const float* __restrict__ W1e, const float* __restrict__ W2e,
    const float* __restrict__ W3e, const int* __restrict__ perm,
    ushort* __restrict__ G1, ushort* __restrict__ G2, ushort* __restrict__ G3,
    int nE)
{
    constexpr int NT = 10;
    __shared__ ushort Bl[NT * 128 * 8];

    const int tid = threadIdx.x;

    for (int idx = tid; idx < NT * 128; idx += 256) {
        int t  = idx >> 7;
        int ks = (idx >> 6) & 1;
        int l  = idx & 63;
        int gp  = t * 16 + (l & 15);
        int kb  = ks * 32 + ((l >> 4) << 3);
        ushort u[8];
        #pragma unroll
        for (int j = 0; j < 8; j++) {
            int k = kb + j;
            float w = 0.f;
            if (gp < 64)      { if (gp < 50) w = W1e[k * 50 + gp]; }
            else if (gp < 96) { int c = gp - 64; if (c < 25) w = W2e[k * 25 + c]; }
            else              { int c = gp - 96; w = W3e[k * 64 + c]; }
            u[j] = f2bf(w);
        }
        *reinterpret_cast<bf16x8*>(&Bl[idx * 8]) = *reinterpret_cast<bf16x8*>(u);
    }
    __syncthreads();   // the only barrier: Bl ready

    const int wv = tid >> 6;
    const int l  = tid & 63;
    const int kq = (l >> 4) << 3;        // this lane's k-offset within K-half
    const int ntiles = (nE + 63) >> 6;

    for (int tile = blockIdx.x; tile < ntiles; tile += gridDim.x) {
        const int r0 = tile << 6;
        const int row = r0 + wv * 16 + (l & 15);
        long long e = (row < nE) ? (long long)perm[row] : 0;
        const float* p = ef + e * 64 + kq;
        float4 a0 = *reinterpret_cast<const float4*>(p);
        float4 a1 = *reinterpret_cast<const float4*>(p + 4);
        float4 a2 = *reinterpret_cast<const float4*>(p + 32);
        float4 a3 = *reinterpret_cast<const float4*>(p + 36);
        bf16x8 A0 = pack_bf8(a0, a1);    // ks = 0
        bf16x8 A1 = pack_bf8(a2, a3);    // ks = 1

        f32x4 acc[NT];
        #pragma unroll
        for (int t = 0; t < NT; t++) acc[t] = (f32x4){0.f, 0.f, 0.f, 0.f};
        #pragma unroll
        for (int t = 0; t < NT; t++) {
            bf16x8 b0 = *reinterpret_cast<const bf16x8*>(&Bl[((t * 2 + 0) * 64 + l) * 8]);
            acc[t] = __builtin_amdgcn_mfma_f32_16x16x32_bf16(A0, b0, acc[t], 0, 0, 0);
            bf16x8 b1 = *reinterpret_cast<const bf16x8*>(&Bl[((t * 2 + 1) * 64 + l) * 8]);
            acc[t] = __builtin_amdgcn_mfma_f32_16x16x32_bf16(A1, b1, acc[t], 0, 0, 0);
        }

        // direct G4 stores (G buffers sized to nE4 -> unconditional)
        const int grpS = (r0 >> 2) + (wv << 2) + (l >> 4);
        const int c = l & 15;
        #pragma unroll
        for (int t = 0; t < NT; t++) {
            uint2 pq;
            pq.x = cvtpk(acc[t][0], acc[t][1]);
            pq.y = cvtpk(acc[t][2], acc[t][3]);
            ushort* Gp; size_t idx;
            if (t < 4)      { Gp = G1; idx = (size_t)grpS * 256 + (t * 16 + c) * 4; }
            else if (t < 6) { Gp = G2; idx = (size_t)grpS * 128 + ((t - 4) * 16 + c) * 4; }
            else            { Gp = G3; idx = (size_t)grpS * 256 + ((t - 6) * 16 + c) * 4; }
            *reinterpret_cast<uint2*>(Gp + idx) = pq;
        }
    }
}

// ---------------- proj_single: one G output (fallback tiers), barrier-free.
template<int NT, int GS>
__global__ __launch_bounds__(256) void proj_single(
    const float* __restrict__ ef,
    const float* __restrict__ W, int wcols,
    const int* __restrict__ perm, ushort* __restrict__ G, int nE)
{
    __shared__ ushort Bl[NT * 128 * 8];

    const int tid = threadIdx.x;

    for (int idx = tid; idx < NT * 128; idx += 256) {
        int t  = idx >> 7;
        int ks = (idx >> 6) & 1;
        int l  = idx & 63;
        int col = t * 16 + (l & 15);
        int kb  = ks * 32 + ((l >> 4) << 3);
        ushort u[8];
        #pragma unroll
        for (int j = 0; j < 8; j++) {
            int k = kb + j;
            float w = (col < wcols) ? W[k * wcols + col] : 0.f;
            u[j] = f2bf(w);
        }
        *reinterpret_cast<bf16x8*>(&Bl[idx * 8]) = *reinterpret_cast<bf16x8*>(u);
    }
    __syncthreads();

    const int wv = tid >> 6;
    const int l  = tid & 63;
    const int kq = (l >> 4) << 3;
    const int ntiles = (nE + 63) >> 6;

    for (int tile = blockIdx.x; tile < ntiles; tile += gridDim.x) {
        const int r0 = tile << 6;
        const int row = r0 + wv * 16 + (l & 15);
        long long e = (row < nE) ? (long long)perm[row] : 0;
        const float* p = ef + e * 64 + kq;
        float4 a0 = *reinterpret_cast<const float4*>(p);
        float4 a1 = *reinterpret_cast<const float4*>(p + 4);
        float4 a2 = *reinterpret_cast<const float4*>(p + 32);
        float4 a3 = *reinterpret_cast<const float4*>(p + 36);
        bf16x8 A0 = pack_bf8(a0, a1);
        bf16x8 A1 = pack_bf8(a2, a3);

        f32x4 acc[NT];
        #pragma unroll
        for (int t = 0; t < NT; t++) acc[t] = (f32x4){0.f, 0.f, 0.f, 0.f};
        #pragma unroll
        for (int t = 0; t < NT; t++) {
            bf16x8 b0 = *reinterpret_cast<const bf16x8*>(&Bl[((t * 2 + 0) * 64 + l) * 8]);
            acc[t] = __builtin_amdgcn_mfma_f32_16x16x32_bf16(A0, b0, acc[t], 0, 0, 0);
            bf16x8 b1 = *reinterpret_cast<const bf16x8*>(&Bl[((t * 2 + 1) * 64 + l) * 8]);
            acc[t] = __builtin_amdgcn_mfma_f32_16x16x32_bf16(A1, b1, acc[t], 0, 0, 0);
        }

        const int grpS = (r0 >> 2) + (wv << 2) + (l >> 4);
        const int c = l & 15;
        #pragma unroll
        for (int t = 0; t < NT; t++) {
            uint2 pq;
            pq.x = cvtpk(acc[t][0], acc[t][1]);
            pq.y = cvtpk(acc[t][2], acc[t][3]);
            size_t idx = (size_t)grpS * (GS * 4) + (t * 16 + c) * 4;
            *reinterpret_cast<uint2*>(G + idx) = pq;
        }
    }
}

// ---------------- agg_csr over G4, fully static indexing (layers 1,2)
template<int NCL, int GS, int SP>
__global__ __launch_bounds__(256) void agg_csr(
    const ushort* __restrict__ G, const int* __restrict__ srcp,
    const int* __restrict__ rowp, const float* __restrict__ P,
    float* __restrict__ ng, int nN)
{
    const int o = threadIdx.x & (NCL - 1);
    const int g = threadIdx.x / NCL;
    const int n = blockIdx.x * (256 / NCL) + g;
    if (n >= nN) return;
    const int s0 = rowp[n], s1 = rowp[n + 1];

    float a[8];
    #pragma unroll
    for (int j = 0; j < 8; j++) a[j] = 0.f;

    if (s0 < s1) {
        const int g0 = s0 >> 2, g1 = (s1 - 1) >> 2;
        for (int grp = g0; grp <= g1; grp++) {
            const ushort* gb = G + (size_t)grp * (GS * 4) + o * 32;
            uint4 c0 = *reinterpret_cast<const uint4*>(gb);
            uint4 c1 = *reinterpret_cast<const uint4*>(gb + 8);
            uint4 c2 = *reinterpret_cast<const uint4*>(gb + 16);
            uint4 c3 = *reinterpret_cast<const uint4*>(gb + 24);
            int4 s4 = *reinterpret_cast<const int4*>(srcp + grp * 4);
            const int rlo = s0 - grp * 4;
            const int rhi = s1 - grp * 4;
            #pragma unroll
            for (int r = 0; r < 4; r++) {
                if (r < rlo || r >= rhi) continue;
                const int s = (r == 0) ? s4.x : (r == 1) ? s4.y : (r == 2) ? s4.z : s4.w;
                const float* pp = P + (size_t)s * SP + o * 8;
                float4 pa = *reinterpret_cast<const float4*>(pp);
                float4 pb = *reinterpret_cast<const float4*>(pp + 4);
                #pragma unroll
                for (int k = 0; k < 8; k++) {
                    uint lo, hi;
                    switch (k) {
                        case 0: lo = c0.x; hi = c0.y; break;
                        case 1: lo = c0.z; hi = c0.w; break;
                        case 2: lo = c1.x; hi = c1.y; break;
                        case 3: lo = c1.z; hi = c1.w; break;
                        case 4: lo = c2.x; hi = c2.y; break;
                        case 5: lo = c2.z; hi = c2.w; break;
                        case 6: lo = c3.x; hi = c3.y; break;
                        default: lo = c3.z; hi = c3.w; break;
                    }
                    const uint q = (r & 2) ? hi : lo;
                    const uint v = (r & 1) ? (q & 0xffff0000u) : (q << 16);
                    const float pv = (k == 0) ? pa.x : (k == 1) ? pa.y
                                   : (k == 2) ? pa.z : (k == 3) ? pa.w
                                   : (k == 4) ? pb.x : (k == 5) ? pb.y
                                   : (k == 6) ? pb.z : pb.w;
                    a[k] += fmaxf(pv + __uint_as_float(v), 0.f);
                }
            }
        }
    }
    float4 w0 = {a[0], a[1], a[2], a[3]}, w1 = {a[4], a[5], a[6], a[7]};
    float* yp = ng + (size_t)n * 64 + o * 8;
    *reinterpret_cast<float4*>(yp)     = w0;
    *reinterpret_cast<float4*>(yp + 4) = w1;
}

// ---------------- agg_apply3: layer-3 CSR reduce + apply + rowsum -> node_sum
__global__ __launch_bounds__(256) void agg_apply3(
    const ushort* __restrict__ G, const int* __restrict__ srcp,
    const int* __restrict__ rowp, const float* __restrict__ P,
    const float* __restrict__ h2,
    const float* __restrict__ Wa3, const float* __restrict__ ba3,
    float* __restrict__ node_sum, int nN)
{
    __shared__ float Wl[89 * 64];
    __shared__ float bl[64];
    const int tid = threadIdx.x;
    for (int idx = tid; idx < 89 * 64; idx += 256) Wl[idx] = Wa3[idx];
    if (tid < 64) bl[tid] = ba3[tid];
    __syncthreads();

    const int o = tid & 7;
    const int n = blockIdx.x * 32 + (tid >> 3);
    if (n >= nN) return;
    const int s0 = rowp[n], s1 = rowp[n + 1];

    float a[8];
    #pragma unroll
    for (int j = 0; j < 8; j++) a[j] = 0.f;

    if (s0 < s1) {
        const int g0 = s0 >> 2, g1 = (s1 - 1) >> 2;
        for (int grp = g0; grp <= g1; grp++) {
            const ushort* gb = G + (size_t)grp * 256 + o * 32;
            uint4 c0 = *reinterpret_cast<const uint4*>(gb);
            uint4 c1 = *reinterpret_cast<const uint4*>(gb + 8);
            uint4 c2 = *reinterpret_cast<const uint4*>(gb + 16);
            uint4 c3 = *reinterpret_cast<const uint4*>(gb + 24);
            int4 s4 = *reinterpret_cast<const int4*>(srcp + grp * 4);
            const int rlo = s0 - grp * 4;
            const int rhi = s1 - grp * 4;
            #pragma unroll
            for (int r = 0; r < 4; r++) {
                if (r < rlo || r >= rhi) continue;
                const int s = (r == 0) ? s4.x : (r == 1) ? s4.y : (r == 2) ? s4.z : s4.w;
                const float* pp = P + (size_t)s * 64 + o * 8;
                float4 pa = *reinterpret_cast<const float4*>(pp);
                float4 pb = *reinterpret_cast<const float4*>(pp + 4);
                #pragma unroll
                for (int k = 0; k < 8; k++) {
                    uint lo, hi;
                    switch (k) {
                        case 0: lo = c0.x; hi = c0.y; break;
                        case 1: lo = c0.z; hi = c0.w; break;
                        case 2: lo = c1.x; hi = c1.y; break;
                        case 3: lo = c1.z; hi = c1.w; break;
                        case 4: lo = c2.x; hi = c2.y; break;
                        case 5: lo = c2.z; hi = c2.w; break;
                        case 6: lo = c3.x; hi = c3.y; break;
                        default: lo = c3.z; hi = c3.w; break;
                    }
                    const uint q = (r & 2) ? hi : lo;
                    const uint v = (r & 1) ? (q & 0xffff0000u) : (q << 16);
                    const float pv = (k == 0) ? pa.x : (k == 1) ? pa.y
                                   : (k == 2) ? pa.z : (k == 3) ? pa.w
                                   : (k == 4) ? pb.x : (k == 5) ? pb.y
                                   : (k == 6) ? pb.z : pb.w;
                    a[k] += fmaxf(pv + __uint_as_float(v), 0.f);
                }
            }
        }
    }

    // ---- apply3: outp[c] = ba + sum_k h2[k]*Wa3[k][o8+c] + sum_j ng[j]*Wa3[25+j][o8+c]
    const int o8 = o * 8;
    float outp[8];
    #pragma unroll
    for (int c = 0; c < 8; c++) outp[c] = bl[o8 + c];

    const float* hr = h2 + (size_t)n * 28;
    for (int k = 0; k < 25; k++) {
        float hv = hr[k];
        #pragma unroll
        for (int c = 0; c < 8; c++)
            outp[c] = fmaf(hv, Wl[k * 64 + o8 + c], outp[c]);
    }

    const int lbase = (tid & 63) & ~7;   // first lane of this 8-lane group
    #pragma unroll
    for (int g = 0; g < 8; g++) {
        float av[8];
        #pragma unroll
        for (int j = 0; j < 8; j++) av[j] = __shfl(a[j], lbase + g, 64);
        #pragma unroll
        for (int j = 0; j < 8; j++) {
            const float* wr = &Wl[(25 + g * 8 + j) * 64 + o8];
            #pragma unroll
            for (int c = 0; c < 8; c++)
                outp[c] = fmaf(av[j], wr[c], outp[c]);
        }
    }

    float s = 0.f;
    #pragma unroll
    for (int c = 0; c < 8; c++) s += fmaxf(outp[c], 0.f);
    s += __shfl_xor(s, 1);
    s += __shfl_xor(s, 2);
    s += __shfl_xor(s, 4);
    if (o == 0) node_sum[n] = s;
}

// ---------------- sort-by-dst (counting sort; 3-phase multi-block scan)
__global__ __launch_bounds__(256) void hist_kernel(
    const int* __restrict__ dst, int* __restrict__ deg, int nE)
{
    for (int e = blockIdx.x * 256 + threadIdx.x; e < nE; e += gridDim.x * 256)
        atomicAdd(&deg[dst[e]], 1);
}

__global__ __launch_bounds__(256) void scan_blksum(
    const int* __restrict__ deg, int* __restrict__ bsum, int nN)
{
    const int t = threadIdx.x;
    const int base = blockIdx.x * 1024;
    int s = 0;
    for (int i = t; i < 1024; i += 256) {
        int id = base + i;
        s += (id < nN) ? deg[id] : 0;
    }
    #pragma unroll
    for (int off = 32; off > 0; off >>= 1) s += __shfl_down(s, off);
    __shared__ int w[4];
    if ((t & 63) == 0) w[t >> 6] = s;
    __syncthreads();
    if (t == 0) bsum[blockIdx.x] = w[0] + w[1] + w[2] + w[3];
}

__global__ __launch_bounds__(256) void scan_top(
    int* __restrict__ bsum, int nB, int* __restrict__ rowp, int nN)
{
    const int t = threadIdx.x;   // nB <= 256
    int v = (t < nB) ? bsum[t] : 0;
    int x = v;
    #pragma unroll
    for (int off = 1; off < 64; off <<= 1) {
        int u = __shfl_up(x, off);
        if ((t & 63) >= off) x += u;
    }
    __shared__ int wsum[4];
    if ((t & 63) == 63) wsum[t >> 6] = x;
    __syncthreads();
    int add = 0;
    #pragma unroll
    for (int i = 0; i < 4; i++) if (i < (t >> 6)) add += wsum[i];
    x += add;
    if (t < nB) bsum[t] = x - v;
    if (t == nB - 1) rowp[nN] = x;
}

__global__ __launch_bounds__(256) void scan_final(
    const int* __restrict__ deg, const int* __restrict__ bsum,
    int* __restrict__ rowp, int nN)
{
    const int t = threadIdx.x;
    const int idx0 = blockIdx.x * 1024 + t * 4;
    int e[4];
    #pragma unroll
    for (int i = 0; i < 4; i++) {
        int id = idx0 + i;
        e[i] = (id < nN) ? deg[id] : 0;
    }
    int tl = e[0] + e[1] + e[2] + e[3];
    int x = tl;
    #pragma unroll
    for (int off = 1; off < 64; off <<= 1) {
        int u = __shfl_up(x, off);
        if ((t & 63) >= off) x += u;
    }
    __shared__ int wsum[4];
    if ((t & 63) == 63) wsum[t >> 6] = x;
    __syncthreads();
    int add = 0;
    #pragma unroll
    for (int i = 0; i < 4; i++) if (i < (t >> 6)) add += wsum[i];
    int run = (x - tl) + add + bsum[blockIdx.x];
    #pragma unroll
    for (int i = 0; i < 4; i++) {
        int id = idx0 + i;
        if (id < nN) rowp[id] = run;
        run += e[i];
    }
}

__global__ __launch_bounds__(256) void scatter_kernel(
    const int* __restrict__ src, const int* __restrict__ dst,
    const int* __restrict__ rowp, int* __restrict__ cursor,
    int* __restrict__ srcp, int* __restrict__ perm, int nE)
{
    for (int e = blockIdx.x * 256 + threadIdx.x; e < nE; e += gridDim.x * 256) {
        int d = dst[e];
        int pos = rowp[d] + atomicAdd(&cursor[d], 1);
        srcp[pos] = src[e];
        perm[pos] = e;
    }
}

// ---------------- VM tower (w2sum folded) + scoring ----------------
__global__ __launch_bounds__(256) void vm_kernel(
    const float* __restrict__ vmf, const float* __restrict__ W1,
    const float* __restrict__ b1, const float* __restrict__ W2,
    const float* __restrict__ b2, float* __restrict__ vm_sum, int nV)
{
    __shared__ float w2s[132];
    const int tid = threadIdx.x;
    if (tid < 128) {
        float s = 0.f;
        for (int o = 0; o < 64; o++) s += W2[tid * 64 + o];
        w2s[tid] = s;
    } else if (tid == 128) {
        float bs = 0.f;
        for (int o = 0; o < 64; o++) bs += b2[o];
        w2s[128] = bs;
    }
    __syncthreads();

    const int lane = tid & 63;
    const int grp  = tid >> 6;
    for (int v = blockIdx.x * 4 + grp; v < nV; v += gridDim.x * 4) {
        const float* vr = vmf + (long long)v * 64;
        float a0 = b1[lane], a1 = b1[lane + 64];
        #pragma unroll 4
        for (int k = 0; k < 64; k += 4) {
            float4 x = *reinterpret_cast<const float4*>(vr + k);
            a0 = fmaf(x.x, W1[(k + 0) * 128 + lane], a0);
            a0 = fmaf(x.y, W1[(k + 1) * 128 + lane], a0);
            a0 = fmaf(x.z, W1[(k + 2) * 128 + lane], a0);
            a0 = fmaf(x.w, W1[(k + 3) * 128 + lane], a0);
            a1 = fmaf(x.x, W1[(k + 0) * 128 + lane + 64], a1);
            a1 = fmaf(x.y, W1[(k + 1) * 128 + lane + 64], a1);
            a1 = fmaf(x.z, W1[(k + 2) * 128 + lane + 64], a1);
            a1 = fmaf(x.w, W1[(k + 3) * 128 + lane + 64], a1);
        }
        float part = fmaxf(a0, 0.f) * w2s[lane] + fmaxf(a1, 0.f) * w2s[lane + 64];
        #pragma unroll
        for (int off = 32; off > 0; off >>= 1) part += __shfl_down(part, off);
        if (lane == 0) vm_sum[v] = part + w2s[128];
    }
}

__global__ __launch_bounds__(256) void score_kernel(
    const int* __restrict__ ec, const int* __restrict__ ev,
    const float* __restrict__ ns, const float* __restrict__ vs,
    float* __restrict__ out, int n)
{
    int i = blockIdx.x * blockDim.x + threadIdx.x;
    if (i < n) {
        float x = ns[ec[i]] + vs[ev[i]];
        out[i] = 1.f / (1.f + expf(-x));
    }
}

extern "C" void kernel_launch(void* const* d_in, const int* in_sizes, int n_in,
                              void* d_out, int out_size, void* d_ws, size_t ws_size,
                              hipStream_t stream)
{
    const float* comp = (const float*)d_in[0];
    const float* ef   = (const float*)d_in[1];
    const float* vmf  = (const float*)d_in[2];
    const int*   src  = (const int*)d_in[3];
    const int*   dst  = (const int*)d_in[4];
    const int*   ecmp = (const int*)d_in[5];
    const int*   evm  = (const int*)d_in[6];
    const float* Wm1 = (const float*)d_in[7];  const float* bm1 = (const float*)d_in[8];
    const float* Wa1 = (const float*)d_in[9];  const float* ba1 = (const float*)d_in[10];
    const float* Wm2 = (const float*)d_in[11]; const float* bm2 = (const float*)d_in[12];
    const float* Wa2 = (const float*)d_in[13]; const float* ba2 = (const float*)d_in[14];
    const float* Wm3 = (const float*)d_in[15]; const float* bm3 = (const float*)d_in[16];
    const float* Wa3 = (const float*)d_in[17]; const float* ba3 = (const float*)d_in[18];
    const float* W1  = (const float*)d_in[19]; const float* b1  = (const float*)d_in[20];
    const float* W2  = (const float*)d_in[21]; const float* b2  = (const float*)d_in[22];

    const int nN = in_sizes[0] / 128;
    const int nE = in_sizes[3];
    const int nV = in_sizes[2] / 64;
    const int nS = in_sizes[5];
    const int nE4 = (nE + 63) & ~63;

    // ---- workspace layout
    float* ws = (float*)d_ws;
    float* bufA     = ws;                        // nN*64: h1(52) / P3(64)
    float* bufB     = bufA + (size_t)nN * 64;    // nN*64: P1(64) / P2(32) / h2(28)
    float* ng       = bufB + (size_t)nN * 64;    // nN*64 neighbor accumulator
    float* node_sum = ng + (size_t)nN * 64;      // nN
    float* vm_sum   = node_sum + nN;             // nV
    int*   iws      = (int*)(((size_t)(vm_sum + nV) + 15) & ~(size_t)15);
    int*   deg      = iws;                       // nN
    int*   cursor   = deg + nN;                  // nN
    int*   rowp     = cursor + nN;               // nN+1
    int*   bsum     = rowp + nN + 1;             // 256
    int*   srcp     = (int*)(((size_t)(bsum + 256) + 15) & ~(size_t)15);  // nE
    int*   perm     = srcp + nE;                 // nE
    size_t Goff = (((size_t)((char*)(perm + nE) - (char*)d_ws)) + 255) & ~(size_t)255;
    ushort* G1 = (ushort*)((char*)d_ws + Goff);
    const size_t g1u = (size_t)nE4 * 64, g2u = (size_t)nE4 * 32, g3u = (size_t)nE4 * 64;
    const bool single = (Goff + (g1u + g2u + g3u) * 2) <= ws_size;
    ushort* G2 = single ? (G1 + g1u) : G1;
    ushort* G3 = single ? (G2 + g2u) : G1;

    float* h1 = bufA;   // stride 52
    float* h2 = bufB;   // stride 28
    float* P1 = bufB;   // stride 64
    float* P2 = bufB;   // stride 32
    float* P3 = bufA;   // stride 64

    const float* We1 = Wm1 + 128 * 50;
    const float* We2 = Wm2 + 50 * 25;
    const float* We3 = Wm3 + 25 * 64;

    const int ngrid  = (nN + 127) / 128;
    const int ptiles = nE4 / 64;
    const int pgrid  = ptiles < 2048 ? ptiles : 2048;
    const int a8grid = (nN * 8 + 255) / 256;
    const int a4grid = (nN * 4 + 255) / 256;
    const int aagrid = (nN + 31) / 32;
    const int sgrid  = (nE + 255) / 256 < 4096 ? (nE + 255) / 256 : 4096;
    const int nB     = (nN + 1023) / 1024;
    const int vgrid  = ((nV + 3) / 4) < 640 ? ((nV + 3) / 4) : 640;

    // ---- one-time counting sort (CSR rowp + sorted srcp + perm)
    hipMemsetAsync(deg, 0, (size_t)(2 * nN) * sizeof(int), stream);  // deg + cursor
    hist_kernel<<<sgrid, 256, 0, stream>>>(dst, deg, nE);
    scan_blksum<<<nB, 256, 0, stream>>>(deg, bsum, nN);
    scan_top<<<1, 256, 0, stream>>>(bsum, nB, rowp, nN);
    scan_final<<<nB, 256, 0, stream>>>(deg, bsum, rowp, nN);
    scatter_kernel<<<sgrid, 256, 0, stream>>>(src, dst, rowp, cursor, srcp, perm, nE);

    // ---- projections (bf16 MFMA over sorted edges, barrier-free, G4 stores)
    if (single)
        proj_fused<<<pgrid, 256, 0, stream>>>(ef, We1, We2, We3, perm, G1, G2, G3, nE);
    else
        proj_single<4, 64><<<pgrid, 256, 0, stream>>>(ef, We1, 50, perm, G1, nE);

    // ================= Layer 1 (D=128 -> 50) =================
    tile_gemm<128,128, 0,0, 64, 50, 64, 16, 8, 0><<<ngrid, 256, 0, stream>>>(
        comp, 128, nullptr, 0, Wm1, bm1, P1, 64, nN);
    agg_csr<8, 64, 64><<<a8grid, 256, 0, stream>>>(G1, srcp, rowp, P1, ng, nN);
    if (!single)
        proj_single<2, 32><<<pgrid, 256, 0, stream>>>(ef, We2, 25, perm, G2, nE);
    // apply1 + P2 fused
    fused_apply_pre<128,128, 50,52, 60, 50, 52, 52, 52, 25, 32, 32, 16, 8, 8, 4>
        <<<ngrid, 256, 0, stream>>>(comp, 128, ng, 64, Wa1, ba1, Wm2, bm2, h1, P2, nN);

    // ================= Layer 2 (50 -> 25) =================
    agg_csr<4, 32, 32><<<a4grid, 256, 0, stream>>>(G2, srcp, rowp, P2, ng, nN);
    if (!single)
        proj_single<4, 64><<<pgrid, 256, 0, stream>>>(ef, We3, 64, perm, G3, nE);
    // apply2 + P3 fused
    fused_apply_pre<50,52, 25,28, 80, 25, 28, 28, 28, 64, 64, 64, 8, 4, 16, 8>
        <<<ngrid, 256, 0, stream>>>(h1, 52, ng, 64, Wa2, ba2, Wm3, bm3, h2, P3, nN);

    // ================= Layer 3: agg + apply + rowsum fused =================
    agg_apply3<<<aagrid, 256, 0, stream>>>(G3, srcp, rowp, P3, h2, Wa3, ba3, node_sum, nN);

    // ================= VM tower (folded) + scores =================
    vm_kernel<<<vgrid, 256, 0, stream>>>(vmf, W1, b1, W2, b2, vm_sum, nV);
    score_kernel<<<(nS + 255) / 256, 256, 0, stream>>>(ecmp, evm, node_sum, vm_sum, (float*)d_out, nS);
}

// Round 17
// 761.065 us; speedup vs baseline: 1.0337x; 1.0337x over previous
//
#include <hip/hip_runtime.h>

typedef unsigned int uint;
typedef unsigned short ushort;
typedef short bf16x8 __attribute__((ext_vector_type(8)));
typedef float f32x4  __attribute__((ext_vector_type(4)));

// ---------------------------------------------------------------------------
// GNN scorer, round 17 (= round 16 + register-prefetch restored in proj):
//   sort: counting-sort by dst -> srcp (sorted), perm (sorted->orig), rowp.
//   proj_fused: bf16 MFMA over sorted edges; per-lane direct A loads in MFMA
//     fragment layout, REGISTER-PIPELINED (next tile's gather issued before
//     current MFMA block), no main-loop barriers, G4 uint2 stores.
//   agg_csr: per-node CSR reduction over G4 (layers 1,2).
//   fused_apply_pre: apply_l GEMM + next layer's pre-GEMM in one kernel.
//   agg_apply3: layer-3 CSR reduction + apply3 + rowsum fused -> node_sum.
//   VM tower folded; sigmoid scores.
// G4 layout: ushort index = (pos>>2)*(GS*4) + col*4 + (pos&3).
// ---------------------------------------------------------------------------

__device__ __forceinline__ ushort f2bf(float f) {
    uint u = __float_as_uint(f);
    u += 0x7FFFu + ((u >> 16) & 1u);          // RNE
    return (ushort)(u >> 16);
}
__device__ __forceinline__ uint cvtpk(float lo, float hi) {
    uint r;
    asm("v_cvt_pk_bf16_f32 %0, %1, %2" : "=v"(r) : "v"(lo), "v"(hi));
    return r;
}
// pack 8 f32 (two float4) -> bf16x8 via 4 cvt_pk (RNE matches f2bf)
__device__ __forceinline__ bf16x8 pack_bf8(const float4& a, const float4& b) {
    uint u0 = cvtpk(a.x, a.y), u1 = cvtpk(a.z, a.w);
    uint u2 = cvtpk(b.x, b.y), u3 = cvtpk(b.z, b.w);
    uint4 q = {u0, u1, u2, u3};
    return *reinterpret_cast<bf16x8*>(&q);
}

// ---------------- node-side tiled GEMM (MODE 0=store, 1=relu+store)
template<int K0, int KP0, int K1, int KP1, int KC, int OUT, int WOUT,
         int NTC, int RPT, int MODE>
__global__ __launch_bounds__(256) void tile_gemm(
    const float* __restrict__ X0, int sx0,
    const float* __restrict__ X1, int sx1,
    const float* __restrict__ Wg, const float* __restrict__ Bg,
    float* __restrict__ Y, int sy, int nR)
{
    constexpr int KPT  = KP0 + KP1;
    constexpr int C4   = KC / 4;
    constexpr int OUTP = 4 * NTC;
    constexpr int NTR  = 256 / NTC;
    constexpr int TR   = NTR * RPT;
    static_assert(TR == 128, "tile must be 128 rows");
    static_assert(KPT % KC == 0, "KC must divide KPT");

    __shared__ float4 Xl[TR * C4];
    __shared__ float4 Wl[KC * NTC];
    __shared__ float  __align__(16) bl[OUTP];

    const int tid = threadIdx.x;
    const int r0  = blockIdx.x * TR;

    for (int idx = tid; idx < OUTP; idx += 256)
        bl[idx] = (Bg != nullptr && idx < OUT) ? Bg[idx] : 0.f;

    const int tc  = tid & (NTC - 1);
    const int tr  = tid / NTC;
    const int key = (RPT * tr) >> 3;

    float4 acc[RPT];
    #pragma unroll
    for (int i = 0; i < RPT; i++) acc[i] = make_float4(0.f, 0.f, 0.f, 0.f);

    for (int kc0 = 0; kc0 < KPT; kc0 += KC) {
        if (kc0 != 0) __syncthreads();
        for (int idx = tid; idx < TR * C4; idx += 256) {
            int r = idx / C4, c = idx - r * C4;
            int col = kc0 + 4 * c;
            int gr = r0 + r;
            float4 v = make_float4(0.f, 0.f, 0.f, 0.f);
            if (gr < nR) {
                if (KP1 == 0 || col < KP0)
                    v = *reinterpret_cast<const float4*>(X0 + (long long)gr * sx0 + col);
                else
                    v = *reinterpret_cast<const float4*>(X1 + (long long)gr * sx1 + (col - KP0));
            }
            int cs = c + ((r >> 3) % C4); if (cs >= C4) cs -= C4;
            Xl[r * C4 + cs] = v;
        }
        for (int idx = tid; idx < KC * OUTP; idx += 256) {
            int kl = idx / OUTP, o = idx - kl * OUTP;
            int k = kc0 + kl;
            float v = 0.f;
            if (o < OUT) {
                if (k < KP0) { if (k < K0) v = Wg[k * OUT + o]; }
                else { int kk = k - KP0; if (kk < K1) v = Wg[(K0 + kk) * OUT + o]; }
            }
            ((float*)Wl)[kl * OUTP + o] = v;
        }
        __syncthreads();

        const int km = key % C4;
        #pragma unroll 4
        for (int k4 = 0; k4 < C4; k4++) {
            int cs = k4 + km; if (cs >= C4) cs -= C4;
            float4 x[RPT];
            #pragma unroll
            for (int i = 0; i < RPT; i++)
                x[i] = Xl[(RPT * tr + i) * C4 + cs];
            #pragma unroll
            for (int kk = 0; kk < 4; kk++) {
                float4 w = Wl[(4 * k4 + kk) * NTC + tc];
                #pragma unroll
                for (int i = 0; i < RPT; i++) {
                    float xs = (kk == 0) ? x[i].x : (kk == 1) ? x[i].y
                             : (kk == 2) ? x[i].z : x[i].w;
                    acc[i].x = fmaf(xs, w.x, acc[i].x);
                    acc[i].y = fmaf(xs, w.y, acc[i].y);
                    acc[i].z = fmaf(xs, w.z, acc[i].z);
                    acc[i].w = fmaf(xs, w.w, acc[i].w);
                }
            }
        }
    }

    const float4 b4 = reinterpret_cast<float4*>(bl)[tc];
    const int o = 4 * tc;

    if (o < WOUT) {
        #pragma unroll
        for (int i = 0; i < RPT; i++) {
            int gr = r0 + RPT * tr + i;
            if (gr < nR) {
                float4 v;
                v.x = acc[i].x + b4.x; v.y = acc[i].y + b4.y;
                v.z = acc[i].z + b4.z; v.w = acc[i].w + b4.w;
                if (MODE == 1) {
                    v.x = fmaxf(v.x, 0.f); v.y = fmaxf(v.y, 0.f);
                    v.z = fmaxf(v.z, 0.f); v.w = fmaxf(v.w, 0.f);
                }
                *reinterpret_cast<float4*>(Y + (long long)gr * sy + o) = v;
            }
        }
    }
}

// ---------------- fused apply_l + pre-GEMM_{l+1}
template<int K0, int KP0, int K1, int KP1, int KC, int OUT1, int WOUT1,
         int OUT1P, int SY1, int OUT2, int OUT2P, int SY2,
         int NTC, int RPT, int NTC2, int RPT2>
__global__ __launch_bounds__(256) void fused_apply_pre(
    const float* __restrict__ X0, int sx0,
    const float* __restrict__ X1, int sx1,
    const float* __restrict__ Wa, const float* __restrict__ ba,
    const float* __restrict__ Wm, const float* __restrict__ bm,
    float* __restrict__ Y1, float* __restrict__ Y2, int nR)
{
    constexpr int KPT  = KP0 + KP1;
    constexpr int C4   = KC / 4;
    constexpr int OUTP = 4 * NTC;
    constexpr int NTR  = 256 / NTC;
    constexpr int TR   = NTR * RPT;
    constexpr int BLSZ = (OUTP > OUT2P) ? OUTP : OUT2P;
    static_assert(TR == 128, "tile must be 128 rows");
    static_assert(KPT % KC == 0, "KC must divide KPT");
    static_assert((256 / NTC2) * RPT2 == 128, "phase2 covers 128 rows");
    static_assert(OUT2P == 4 * NTC2, "phase2 col tiling");
    static_assert(128 * OUT1P <= TR * C4 * 4, "Hl fits in Xl");
    static_assert(OUT1 * OUT2P <= KC * NTC * 4, "Wm fits in Wl");

    __shared__ float4 Xl[TR * C4];
    __shared__ float4 Wl[KC * NTC];
    __shared__ float  __align__(16) bl[BLSZ];
    float* Hl = (float*)Xl;           // aliased: valid only after phase-1 K-loop

    const int tid = threadIdx.x;
    const int r0  = blockIdx.x * TR;

    for (int idx = tid; idx < OUTP; idx += 256)
        bl[idx] = (idx < OUT1) ? ba[idx] : 0.f;

    const int tc  = tid & (NTC - 1);
    const int tr  = tid / NTC;
    const int key = (RPT * tr) >> 3;

    float4 acc[RPT];
    #pragma unroll
    for (int i = 0; i < RPT; i++) acc[i] = make_float4(0.f, 0.f, 0.f, 0.f);

    for (int kc0 = 0; kc0 < KPT; kc0 += KC) {
        if (kc0 != 0) __syncthreads();
        for (int idx = tid; idx < TR * C4; idx += 256) {
            int r = idx / C4, c = idx - r * C4;
            int col = kc0 + 4 * c;
            int gr = r0 + r;
            float4 v = make_float4(0.f, 0.f, 0.f, 0.f);
            if (gr < nR) {
                if (KP1 == 0 || col < KP0)
                    v = *reinterpret_cast<const float4*>(X0 + (long long)gr * sx0 + col);
                else
                    v = *reinterpret_cast<const float4*>(X1 + (long long)gr * sx1 + (col - KP0));
            }
            int cs = c + ((r >> 3) % C4); if (cs >= C4) cs -= C4;
            Xl[r * C4 + cs] = v;
        }
        for (int idx = tid; idx < KC * OUTP; idx += 256) {
            int kl = idx / OUTP, o = idx - kl * OUTP;
            int k = kc0 + kl;
            float v = 0.f;
            if (o < OUT1) {
                if (k < KP0) { if (k < K0) v = Wa[k * OUT1 + o]; }
                else { int kk = k - KP0; if (kk < K1) v = Wa[(K0 + kk) * OUT1 + o]; }
            }
            ((float*)Wl)[kl * OUTP + o] = v;
        }
        __syncthreads();

        const int km = key % C4;
        #pragma unroll 4
        for (int k4 = 0; k4 < C4; k4++) {
            int cs = k4 + km; if (cs >= C4) cs -= C4;
            float4 x[RPT];
            #pragma unroll
            for (int i = 0; i < RPT; i++)
                x[i] = Xl[(RPT * tr + i) * C4 + cs];
            #pragma unroll
            for (int kk = 0; kk < 4; kk++) {
                float4 w = Wl[(4 * k4 + kk) * NTC + tc];
                #pragma unroll
                for (int i = 0; i < RPT; i++) {
                    float xs = (kk == 0) ? x[i].x : (kk == 1) ? x[i].y
                             : (kk == 2) ? x[i].z : x[i].w;
                    acc[i].x = fmaf(xs, w.x, acc[i].x);
                    acc[i].y = fmaf(xs, w.y, acc[i].y);
                    acc[i].z = fmaf(xs, w.z, acc[i].z);
                    acc[i].w = fmaf(xs, w.w, acc[i].w);
                }
            }
        }
    }

    const float4 b4 = reinterpret_cast<float4*>(bl)[tc];
    const int o = 4 * tc;

    __syncthreads();   // Xl/Wl/bl free: K-loop and bias read done block-wide

    // phase-1 epilogue: relu, global store, Hl stash (zeros for OOB rows)
    if (o < WOUT1) {
        #pragma unroll
        for (int i = 0; i < RPT; i++) {
            int lr = RPT * tr + i;
            int gr = r0 + lr;
            float4 v;
            v.x = fmaxf(acc[i].x + b4.x, 0.f); v.y = fmaxf(acc[i].y + b4.y, 0.f);
            v.z = fmaxf(acc[i].z + b4.z, 0.f); v.w = fmaxf(acc[i].w + b4.w, 0.f);
            if (gr >= nR) v = make_float4(0.f, 0.f, 0.f, 0.f);
            if (o < OUT1P)
                *reinterpret_cast<float4*>(Hl + lr * OUT1P + o) = v;
            if (gr < nR)
                *reinterpret_cast<float4*>(Y1 + (long long)gr * SY1 + o) = v;
        }
    }
    // stage phase-2 W (zero-padded cols) + bias into Wl/bl regions
    for (int idx = tid; idx < OUT1 * OUT2P; idx += 256) {
        int k = idx / OUT2P, oc = idx - k * OUT2P;
        ((float*)Wl)[idx] = (oc < OUT2) ? Wm[k * OUT2 + oc] : 0.f;
    }
    for (int idx = tid; idx < OUT2P; idx += 256)
        bl[idx] = (idx < OUT2) ? bm[idx] : 0.f;
    __syncthreads();

    // phase 2: P = h @ Wm + bm
    const int tc2 = tid & (NTC2 - 1);
    const int tr2 = tid / NTC2;
    float4 acc2[RPT2];
    #pragma unroll
    for (int i = 0; i < RPT2; i++) acc2[i] = make_float4(0.f, 0.f, 0.f, 0.f);

    #pragma unroll 4
    for (int k = 0; k < OUT1; k++) {
        float4 w = reinterpret_cast<float4*>((float*)Wl)[k * NTC2 + tc2];
        #pragma unroll
        for (int i = 0; i < RPT2; i++) {
            float xs = Hl[(RPT2 * tr2 + i) * OUT1P + k];
            acc2[i].x = fmaf(xs, w.x, acc2[i].x);
            acc2[i].y = fmaf(xs, w.y, acc2[i].y);
            acc2[i].z = fmaf(xs, w.z, acc2[i].z);
            acc2[i].w = fmaf(xs, w.w, acc2[i].w);
        }
    }
    const float4 b2 = reinterpret_cast<float4*>(bl)[tc2];
    #pragma unroll
    for (int i = 0; i < RPT2; i++) {
        int gr = r0 + RPT2 * tr2 + i;
        if (gr < nR) {
            float4 v;
            v.x = acc2[i].x + b2.x; v.y = acc2[i].y + b2.y;
            v.z = acc2[i].z + b2.z; v.w = acc2[i].w + b2.w;
            *reinterpret_cast<float4*>(Y2 + (long long)gr * SY2 + 4 * tc2) = v;
        }
    }
}

// ---------------- proj_fused: barrier-free + register-pipelined A gather.
// A frag layout (16x16x32 bf16): lane l holds row (l&15), k = (l>>4)*8+j,
// ks selects K-half (cols +ks*32). Wave wv owns rows wv*16..+15 of the tile.
__global__ __launch_bounds__(256) void proj_fused(
    const float* __restrict__ ef,
    const float* __restrict__ W1e, const float* __restrict__ W2e,
    const float* __restrict__ W3e, const int* __restrict__ perm,
    ushort* __restrict__ G1, ushort* __restrict__ G2, ushort* __restrict__ G3,
    int nE)
{
    constexpr int NT = 10;
    __shared__ ushort Bl[NT * 128 * 8];

    const int tid = threadIdx.x;

    for (int idx = tid; idx < NT * 128; idx += 256) {
        int t  = idx >> 7;
        int ks = (idx >> 6) & 1;
        int l  = idx & 63;
        int gp  = t * 16 + (l & 15);
        int kb  = ks * 32 + ((l >> 4) << 3);
        ushort u[8];
        #pragma unroll
        for (int j = 0; j < 8; j++) {
            int k = kb + j;
            float w = 0.f;
            if (gp < 64)      { if (gp < 50) w = W1e[k * 50 + gp]; }
            else if (gp < 96) { int c = gp - 64; if (c < 25) w = W2e[k * 25 + c]; }
            else              { int c = gp - 96; w = W3e[k * 64 + c]; }
            u[j] = f2bf(w);
        }
        *reinterpret_cast<bf16x8*>(&Bl[idx * 8]) = *reinterpret_cast<bf16x8*>(u);
    }
    __syncthreads();   // the only barrier: Bl ready

    const int wv = tid >> 6;
    const int l  = tid & 63;
    const int kq = (l >> 4) << 3;        // this lane's k-offset within K-half
    const int lrow = wv * 16 + (l & 15);
    const int ntiles = (nE + 63) >> 6;

    float4 n0, n1, n2, n3;
    int tile = blockIdx.x;
    if (tile < ntiles) {
        int row = (tile << 6) + lrow;
        long long e = (row < nE) ? (long long)perm[row] : 0;
        const float* p = ef + e * 64 + kq;
        n0 = *reinterpret_cast<const float4*>(p);
        n1 = *reinterpret_cast<const float4*>(p + 4);
        n2 = *reinterpret_cast<const float4*>(p + 32);
        n3 = *reinterpret_cast<const float4*>(p + 36);
    }

    for (; tile < ntiles; tile += gridDim.x) {
        const int r0 = tile << 6;
        bf16x8 A0 = pack_bf8(n0, n1);    // waits on current gather here
        bf16x8 A1 = pack_bf8(n2, n3);

        // issue NEXT tile's gather now; latency hides under MFMA + stores
        int nxt = tile + gridDim.x;
        if (nxt < ntiles) {
            int row = (nxt << 6) + lrow;
            long long e = (row < nE) ? (long long)perm[row] : 0;
            const float* p = ef + e * 64 + kq;
            n0 = *reinterpret_cast<const float4*>(p);
            n1 = *reinterpret_cast<const float4*>(p + 4);
            n2 = *reinterpret_cast<const float4*>(p + 32);
            n3 = *reinterpret_cast<const float4*>(p + 36);
        }

        f32x4 acc[NT];
        #pragma unroll
        for (int t = 0; t < NT; t++) acc[t] = (f32x4){0.f, 0.f, 0.f, 0.f};
        #pragma unroll
        for (int t = 0; t < NT; t++) {
            bf16x8 b0 = *reinterpret_cast<const bf16x8*>(&Bl[((t * 2 + 0) * 64 + l) * 8]);
            acc[t] = __builtin_amdgcn_mfma_f32_16x16x32_bf16(A0, b0, acc[t], 0, 0, 0);
            bf16x8 b1 = *reinterpret_cast<const bf16x8*>(&Bl[((t * 2 + 1) * 64 + l) * 8]);
            acc[t] = __builtin_amdgcn_mfma_f32_16x16x32_bf16(A1, b1, acc[t], 0, 0, 0);
        }

        // direct G4 stores (G buffers sized to nE4 -> unconditional)
        const int grpS = (r0 >> 2) + (wv << 2) + (l >> 4);
        const int c = l & 15;
        #pragma unroll
        for (int t = 0; t < NT; t++) {
            uint2 pq;
            pq.x = cvtpk(acc[t][0], acc[t][1]);
            pq.y = cvtpk(acc[t][2], acc[t][3]);
            ushort* Gp; size_t idx;
            if (t < 4)      { Gp = G1; idx = (size_t)grpS * 256 + (t * 16 + c) * 4; }
            else if (t < 6) { Gp = G2; idx = (size_t)grpS * 128 + ((t - 4) * 16 + c) * 4; }
            else            { Gp = G3; idx = (size_t)grpS * 256 + ((t - 6) * 16 + c) * 4; }
            *reinterpret_cast<uint2*>(Gp + idx) = pq;
        }
    }
}

// ---------------- proj_single: one G output (fallback tiers), pipelined.
template<int NT, int GS>
__global__ __launch_bounds__(256) void proj_single(
    const float* __restrict__ ef,
    const float* __restrict__ W, int wcols,
    const int* __restrict__ perm, ushort* __restrict__ G, int nE)
{
    __shared__ ushort Bl[NT * 128 * 8];

    const int tid = threadIdx.x;

    for (int idx = tid; idx < NT * 128; idx += 256) {
        int t  = idx >> 7;
        int ks = (idx >> 6) & 1;
        int l  = idx & 63;
        int col = t * 16 + (l & 15);
        int kb  = ks * 32 + ((l >> 4) << 3);
        ushort u[8];
        #pragma unroll
        for (int j = 0; j < 8; j++) {
            int k = kb + j;
            float w = (col < wcols) ? W[k * wcols + col] : 0.f;
            u[j] = f2bf(w);
        }
        *reinterpret_cast<bf16x8*>(&Bl[idx * 8]) = *reinterpret_cast<bf16x8*>(u);
    }
    __syncthreads();

    const int wv = tid >> 6;
    const int l  = tid & 63;
    const int kq = (l >> 4) << 3;
    const int lrow = wv * 16 + (l & 15);
    const int ntiles = (nE + 63) >> 6;

    float4 n0, n1, n2, n3;
    int tile = blockIdx.x;
    if (tile < ntiles) {
        int row = (tile << 6) + lrow;
        long long e = (row < nE) ? (long long)perm[row] : 0;
        const float* p = ef + e * 64 + kq;
        n0 = *reinterpret_cast<const float4*>(p);
        n1 = *reinterpret_cast<const float4*>(p + 4);
        n2 = *reinterpret_cast<const float4*>(p + 32);
        n3 = *reinterpret_cast<const float4*>(p + 36);
    }

    for (; tile < ntiles; tile += gridDim.x) {
        const int r0 = tile << 6;
        bf16x8 A0 = pack_bf8(n0, n1);
        bf16x8 A1 = pack_bf8(n2, n3);

        int nxt = tile + gridDim.x;
        if (nxt < ntiles) {
            int row = (nxt << 6) + lrow;
            long long e = (row < nE) ? (long long)perm[row] : 0;
            const float* p = ef + e * 64 + kq;
            n0 = *reinterpret_cast<const float4*>(p);
            n1 = *reinterpret_cast<const float4*>(p + 4);
            n2 = *reinterpret_cast<const float4*>(p + 32);
            n3 = *reinterpret_cast<const float4*>(p + 36);
        }

        f32x4 acc[NT];
        #pragma unroll
        for (int t = 0; t < NT; t++) acc[t] = (f32x4){0.f, 0.f, 0.f, 0.f};
        #pragma unroll
        for (int t = 0; t < NT; t++) {
            bf16x8 b0 = *reinterpret_cast<const bf16x8*>(&Bl[((t * 2 + 0) * 64 + l) * 8]);
            acc[t] = __builtin_amdgcn_mfma_f32_16x16x32_bf16(A0, b0, acc[t], 0, 0, 0);
            bf16x8 b1 = *reinterpret_cast<const bf16x8*>(&Bl[((t * 2 + 1) * 64 + l) * 8]);
            acc[t] = __builtin_amdgcn_mfma_f32_16x16x32_bf16(A1, b1, acc[t], 0, 0, 0);
        }

        const int grpS = (r0 >> 2) + (wv << 2) + (l >> 4);
        const int c = l & 15;
        #pragma unroll
        for (int t = 0; t < NT; t++) {
            uint2 pq;
            pq.x = cvtpk(acc[t][0], acc[t][1]);
            pq.y = cvtpk(acc[t][2], acc[t][3]);
            size_t idx = (size_t)grpS * (GS * 4) + (t * 16 + c) * 4;
            *reinterpret_cast<uint2*>(G + idx) = pq;
        }
    }
}

// ---------------- agg_csr over G4, fully static indexing (layers 1,2)
template<int NCL, int GS, int SP>
__global__ __launch_bounds__(256) void agg_csr(
    const ushort* __restrict__ G, const int* __restrict__ srcp,
    const int* __restrict__ rowp, const float* __restrict__ P,
    float* __restrict__ ng, int nN)
{
    const int o = threadIdx.x & (NCL - 1);
    const int g = threadIdx.x / NCL;
    const int n = blockIdx.x * (256 / NCL) + g;
    if (n >= nN) return;
    const int s0 = rowp[n], s1 = rowp[n + 1];

    float a[8];
    #pragma unroll
    for (int j = 0; j < 8; j++) a[j] = 0.f;

    if (s0 < s1) {
        const int g0 = s0 >> 2, g1 = (s1 - 1) >> 2;
        for (int grp = g0; grp <= g1; grp++) {
            const ushort* gb = G + (size_t)grp * (GS * 4) + o * 32;
            uint4 c0 = *reinterpret_cast<const uint4*>(gb);
            uint4 c1 = *reinterpret_cast<const uint4*>(gb + 8);
            uint4 c2 = *reinterpret_cast<const uint4*>(gb + 16);
            uint4 c3 = *reinterpret_cast<const uint4*>(gb + 24);
            int4 s4 = *reinterpret_cast<const int4*>(srcp + grp * 4);
            const int rlo = s0 - grp * 4;
            const int rhi = s1 - grp * 4;
            #pragma unroll
            for (int r = 0; r < 4; r++) {
                if (r < rlo || r >= rhi) continue;
                const int s = (r == 0) ? s4.x : (r == 1) ? s4.y : (r == 2) ? s4.z : s4.w;
                const float* pp = P + (size_t)s * SP + o * 8;
                float4 pa = *reinterpret_cast<const float4*>(pp);
                float4 pb = *reinterpret_cast<const float4*>(pp + 4);
                #pragma unroll
                for (int k = 0; k < 8; k++) {
                    uint lo, hi;
                    switch (k) {
                        case 0: lo = c0.x; hi = c0.y; break;
                        case 1: lo = c0.z; hi = c0.w; break;
                        case 2: lo = c1.x; hi = c1.y; break;
                        case 3: lo = c1.z; hi = c1.w; break;
                        case 4: lo = c2.x; hi = c2.y; break;
                        case 5: lo = c2.z; hi = c2.w; break;
                        case 6: lo = c3.x; hi = c3.y; break;
                        default: lo = c3.z; hi = c3.w; break;
                    }
                    const uint q = (r & 2) ? hi : lo;
                    const uint v = (r & 1) ? (q & 0xffff0000u) : (q << 16);
                    const float pv = (k == 0) ? pa.x : (k == 1) ? pa.y
                                   : (k == 2) ? pa.z : (k == 3) ? pa.w
                                   : (k == 4) ? pb.x : (k == 5) ? pb.y
                                   : (k == 6) ? pb.z : pb.w;
                    a[k] += fmaxf(pv + __uint_as_float(v), 0.f);
                }
            }
        }
    }
    float4 w0 = {a[0], a[1], a[2], a[3]}, w1 = {a[4], a[5], a[6], a[7]};
    float* yp = ng + (size_t)n * 64 + o * 8;
    *reinterpret_cast<float4*>(yp)     = w0;
    *reinterpret_cast<float4*>(yp + 4) = w1;
}

// ---------------- agg_apply3: layer-3 CSR reduce + apply + rowsum -> node_sum
__global__ __launch_bounds__(256) void agg_apply3(
    const ushort* __restrict__ G, const int* __restrict__ srcp,
    const int* __restrict__ rowp, const float* __restrict__ P,
    const float* __restrict__ h2,
    const float* __restrict__ Wa3, const float* __restrict__ ba3,
    float* __restrict__ node_sum, int nN)
{
    __shared__ float Wl[89 * 64];
    __shared__ float bl[64];
    const int tid = threadIdx.x;
    for (int idx = tid; idx < 89 * 64; idx += 256) Wl[idx] = Wa3[idx];
    if (tid < 64) bl[tid] = ba3[tid];
    __syncthreads();

    const int o = tid & 7;
    const int n = blockIdx.x * 32 + (tid >> 3);
    if (n >= nN) return;
    const int s0 = rowp[n], s1 = rowp[n + 1];

    float a[8];
    #pragma unroll
    for (int j = 0; j < 8; j++) a[j] = 0.f;

    if (s0 < s1) {
        const int g0 = s0 >> 2, g1 = (s1 - 1) >> 2;
        for (int grp = g0; grp <= g1; grp++) {
            const ushort* gb = G + (size_t)grp * 256 + o * 32;
            uint4 c0 = *reinterpret_cast<const uint4*>(gb);
            uint4 c1 = *reinterpret_cast<const uint4*>(gb + 8);
            uint4 c2 = *reinterpret_cast<const uint4*>(gb + 16);
            uint4 c3 = *reinterpret_cast<const uint4*>(gb + 24);
            int4 s4 = *reinterpret_cast<const int4*>(srcp + grp * 4);
            const int rlo = s0 - grp * 4;
            const int rhi = s1 - grp * 4;
            #pragma unroll
            for (int r = 0; r < 4; r++) {
                if (r < rlo || r >= rhi) continue;
                const int s = (r == 0) ? s4.x : (r == 1) ? s4.y : (r == 2) ? s4.z : s4.w;
                const float* pp = P + (size_t)s * 64 + o * 8;
                float4 pa = *reinterpret_cast<const float4*>(pp);
                float4 pb = *reinterpret_cast<const float4*>(pp + 4);
                #pragma unroll
                for (int k = 0; k < 8; k++) {
                    uint lo, hi;
                    switch (k) {
                        case 0: lo = c0.x; hi = c0.y; break;
                        case 1: lo = c0.z; hi = c0.w; break;
                        case 2: lo = c1.x; hi = c1.y; break;
                        case 3: lo = c1.z; hi = c1.w; break;
                        case 4: lo = c2.x; hi = c2.y; break;
                        case 5: lo = c2.z; hi = c2.w; break;
                        case 6: lo = c3.x; hi = c3.y; break;
                        default: lo = c3.z; hi = c3.w; break;
                    }
                    const uint q = (r & 2) ? hi : lo;
                    const uint v = (r & 1) ? (q & 0xffff0000u) : (q << 16);
                    const float pv = (k == 0) ? pa.x : (k == 1) ? pa.y
                                   : (k == 2) ? pa.z : (k == 3) ? pa.w
                                   : (k == 4) ? pb.x : (k == 5) ? pb.y
                                   : (k == 6) ? pb.z : pb.w;
                    a[k] += fmaxf(pv + __uint_as_float(v), 0.f);
                }
            }
        }
    }

    // ---- apply3: outp[c] = ba + sum_k h2[k]*Wa3[k][o8+c] + sum_j ng[j]*Wa3[25+j][o8+c]
    const int o8 = o * 8;
    float outp[8];
    #pragma unroll
    for (int c = 0; c < 8; c++) outp[c] = bl[o8 + c];

    const float* hr = h2 + (size_t)n * 28;
    for (int k = 0; k < 25; k++) {
        float hv = hr[k];
        #pragma unroll
        for (int c = 0; c < 8; c++)
            outp[c] = fmaf(hv, Wl[k * 64 + o8 + c], outp[c]);
    }

    const int lbase = (tid & 63) & ~7;   // first lane of this 8-lane group
    #pragma unroll
    for (int g = 0; g < 8; g++) {
        float av[8];
        #pragma unroll
        for (int j = 0; j < 8; j++) av[j] = __shfl(a[j], lbase + g, 64);
        #pragma unroll
        for (int j = 0; j < 8; j++) {
            const float* wr = &Wl[(25 + g * 8 + j) * 64 + o8];
            #pragma unroll
            for (int c = 0; c < 8; c++)
                outp[c] = fmaf(av[j], wr[c], outp[c]);
        }
    }

    float s = 0.f;
    #pragma unroll
    for (int c = 0; c < 8; c++) s += fmaxf(outp[c], 0.f);
    s += __shfl_xor(s, 1);
    s += __shfl_xor(s, 2);
    s += __shfl_xor(s, 4);
    if (o == 0) node_sum[n] = s;
}

// ---------------- sort-by-dst (counting sort; 3-phase multi-block scan)
__global__ __launch_bounds__(256) void hist_kernel(
    const int* __restrict__ dst, int* __restrict__ deg, int nE)
{
    for (int e = blockIdx.x * 256 + threadIdx.x; e < nE; e += gridDim.x * 256)
        atomicAdd(&deg[dst[e]], 1);
}

__global__ __launch_bounds__(256) void scan_blksum(
    const int* __restrict__ deg, int* __restrict__ bsum, int nN)
{
    const int t = threadIdx.x;
    const int base = blockIdx.x * 1024;
    int s = 0;
    for (int i = t; i < 1024; i += 256) {
        int id = base + i;
        s += (id < nN) ? deg[id] : 0;
    }
    #pragma unroll
    for (int off = 32; off > 0; off >>= 1) s += __shfl_down(s, off);
    __shared__ int w[4];
    if ((t & 63) == 0) w[t >> 6] = s;
    __syncthreads();
    if (t == 0) bsum[blockIdx.x] = w[0] + w[1] + w[2] + w[3];
}

__global__ __launch_bounds__(256) void scan_top(
    int* __restrict__ bsum, int nB, int* __restrict__ rowp, int nN)
{
    const int t = threadIdx.x;   // nB <= 256
    int v = (t < nB) ? bsum[t] : 0;
    int x = v;
    #pragma unroll
    for (int off = 1; off < 64; off <<= 1) {
        int u = __shfl_up(x, off);
        if ((t & 63) >= off) x += u;
    }
    __shared__ int wsum[4];
    if ((t & 63) == 63) wsum[t >> 6] = x;
    __syncthreads();
    int add = 0;
    #pragma unroll
    for (int i = 0; i < 4; i++) if (i < (t >> 6)) add += wsum[i];
    x += add;
    if (t < nB) bsum[t] = x - v;
    if (t == nB - 1) rowp[nN] = x;
}

__global__ __launch_bounds__(256) void scan_final(
    const int* __restrict__ deg, const int* __restrict__ bsum,
    int* __restrict__ rowp, int nN)
{
    const int t = threadIdx.x;
    const int idx0 = blockIdx.x * 1024 + t * 4;
    int e[4];
    #pragma unroll
    for (int i = 0; i < 4; i++) {
        int id = idx0 + i;
        e[i] = (id < nN) ? deg[id] : 0;
    }
    int tl = e[0] + e[1] + e[2] + e[3];
    int x = tl;
    #pragma unroll
    for (int off = 1; off < 64; off <<= 1) {
        int u = __shfl_up(x, off);
        if ((t & 63) >= off) x += u;
    }
    __shared__ int wsum[4];
    if ((t & 63) == 63) wsum[t >> 6] = x;
    __syncthreads();
    int add = 0;
    #pragma unroll
    for (int i = 0; i < 4; i++) if (i < (t >> 6)) add += wsum[i];
    int run = (x - tl) + add + bsum[blockIdx.x];
    #pragma unroll
    for (int i = 0; i < 4; i++) {
        int id = idx0 + i;
        if (id < nN) rowp[id] = run;
        run += e[i];
    }
}

__global__ __launch_bounds__(256) void scatter_kernel(
    const int* __restrict__ src, const int* __restrict__ dst,
    const int* __restrict__ rowp, int* __restrict__ cursor,
    int* __restrict__ srcp, int* __restrict__ perm, int nE)
{
    for (int e = blockIdx.x * 256 + threadIdx.x; e < nE; e += gridDim.x * 256) {
        int d = dst[e];
        int pos = rowp[d] + atomicAdd(&cursor[d], 1);
        srcp[pos] = src[e];
        perm[pos] = e;
    }
}

// ---------------- VM tower (w2sum folded) + scoring ----------------
__global__ __launch_bounds__(256) void vm_kernel(
    const float* __restrict__ vmf, const float* __restrict__ W1,
    const float* __restrict__ b1, const float* __restrict__ W2,
    const float* __restrict__ b2, float* __restrict__ vm_sum, int nV)
{
    __shared__ float w2s[132];
    const int tid = threadIdx.x;
    if (tid < 128) {
        float s = 0.f;
        for (int o = 0; o < 64; o++) s += W2[tid * 64 + o];
        w2s[tid] = s;
    } else if (tid == 128) {
        float bs = 0.f;
        for (int o = 0; o < 64; o++) bs += b2[o];
        w2s[128] = bs;
    }
    __syncthreads();

    const int lane = tid & 63;
    const int grp  = tid >> 6;
    for (int v = blockIdx.x * 4 + grp; v < nV; v += gridDim.x * 4) {
        const float* vr = vmf + (long long)v * 64;
        float a0 = b1[lane], a1 = b1[lane + 64];
        #pragma unroll 4
        for (int k = 0; k < 64; k += 4) {
            float4 x = *reinterpret_cast<const float4*>(vr + k);
            a0 = fmaf(x.x, W1[(k + 0) * 128 + lane], a0);
            a0 = fmaf(x.y, W1[(k + 1) * 128 + lane], a0);
            a0 = fmaf(x.z, W1[(k + 2) * 128 + lane], a0);
            a0 = fmaf(x.w, W1[(k + 3) * 128 + lane], a0);
            a1 = fmaf(x.x, W1[(k + 0) * 128 + lane + 64], a1);
            a1 = fmaf(x.y, W1[(k + 1) * 128 + lane + 64], a1);
            a1 = fmaf(x.z, W1[(k + 2) * 128 + lane + 64], a1);
            a1 = fmaf(x.w, W1[(k + 3) * 128 + lane + 64], a1);
        }
        float part = fmaxf(a0, 0.f) * w2s[lane] + fmaxf(a1, 0.f) * w2s[lane + 64];
        #pragma unroll
        for (int off = 32; off > 0; off >>= 1) part += __shfl_down(part, off);
        if (lane == 0) vm_sum[v] = part + w2s[128];
    }
}

__global__ __launch_bounds__(256) void score_kernel(
    const int* __restrict__ ec, const int* __restrict__ ev,
    const float* __restrict__ ns, const float* __restrict__ vs,
    float* __restrict__ out, int n)
{
    int i = blockIdx.x * blockDim.x + threadIdx.x;
    if (i < n) {
        float x = ns[ec[i]] + vs[ev[i]];
        out[i] = 1.f / (1.f + expf(-x));
    }
}

extern "C" void kernel_launch(void* const* d_in, const int* in_sizes, int n_in,
                              void* d_out, int out_size, void* d_ws, size_t ws_size,
                              hipStream_t stream)
{
    const float* comp = (const float*)d_in[0];
    const float* ef   = (const float*)d_in[1];
    const float* vmf  = (const float*)d_in[2];
    const int*   src  = (const int*)d_in[3];
    const int*   dst  = (const int*)d_in[4];
    const int*   ecmp = (const int*)d_in[5];
    const int*   evm  = (const int*)d_in[6];
    const float* Wm1 = (const float*)d_in[7];  const float* bm1 = (const float*)d_in[8];
    const float* Wa1 = (const float*)d_in[9];  const float* ba1 = (const float*)d_in[10];
    const float* Wm2 = (const float*)d_in[11]; const float* bm2 = (const float*)d_in[12];
    const float* Wa2 = (const float*)d_in[13]; const float* ba2 = (const float*)d_in[14];
    const float* Wm3 = (const float*)d_in[15]; const float* bm3 = (const float*)d_in[16];
    const float* Wa3 = (const float*)d_in[17]; const float* ba3 = (const float*)d_in[18];
    const float* W1  = (const float*)d_in[19]; const float* b1  = (const float*)d_in[20];
    const float* W2  = (const float*)d_in[21]; const float* b2  = (const float*)d_in[22];

    const int nN = in_sizes[0] / 128;
    const int nE = in_sizes[3];
    const int nV = in_sizes[2] / 64;
    const int nS = in_sizes[5];
    const int nE4 = (nE + 63) & ~63;

    // ---- workspace layout
    float* ws = (float*)d_ws;
    float* bufA     = ws;                        // nN*64: h1(52) / P3(64)
    float* bufB     = bufA + (size_t)nN * 64;    // nN*64: P1(64) / P2(32) / h2(28)
    float* ng       = bufB + (size_t)nN * 64;    // nN*64 neighbor accumulator
    float* node_sum = ng + (size_t)nN * 64;      // nN
    float* vm_sum   = node_sum + nN;             // nV
    int*   iws      = (int*)(((size_t)(vm_sum + nV) + 15) & ~(size_t)15);
    int*   deg      = iws;                       // nN
    int*   cursor   = deg + nN;                  // nN
    int*   rowp     = cursor + nN;               // nN+1
    int*   bsum     = rowp + nN + 1;             // 256
    int*   srcp     = (int*)(((size_t)(bsum + 256) + 15) & ~(size_t)15);  // nE
    int*   perm     = srcp + nE;                 // nE
    size_t Goff = (((size_t)((char*)(perm + nE) - (char*)d_ws)) + 255) & ~(size_t)255;
    ushort* G1 = (ushort*)((char*)d_ws + Goff);
    const size_t g1u = (size_t)nE4 * 64, g2u = (size_t)nE4 * 32, g3u = (size_t)nE4 * 64;
    const bool single = (Goff + (g1u + g2u + g3u) * 2) <= ws_size;
    ushort* G2 = single ? (G1 + g1u) : G1;
    ushort* G3 = single ? (G2 + g2u) : G1;

    float* h1 = bufA;   // stride 52
    float* h2 = bufB;   // stride 28
    float* P1 = bufB;   // stride 64
    float* P2 = bufB;   // stride 32
    float* P3 = bufA;   // stride 64

    const float* We1 = Wm1 + 128 * 50;
    const float* We2 = Wm2 + 50 * 25;
    const float* We3 = Wm3 + 25 * 64;

    const int ngrid  = (nN + 127) / 128;
    const int ptiles = nE4 / 64;
    const int pgrid  = ptiles < 2048 ? ptiles : 2048;
    const int a8grid = (nN * 8 + 255) / 256;
    const int a4grid = (nN * 4 + 255) / 256;
    const int aagrid = (nN + 31) / 32;
    const int sgrid  = (nE + 255) / 256 < 4096 ? (nE + 255) / 256 : 4096;
    const int nB     = (nN + 1023) / 1024;
    const int vgrid  = ((nV + 3) / 4) < 640 ? ((nV + 3) / 4) : 640;

    // ---- one-time counting sort (CSR rowp + sorted srcp + perm)
    hipMemsetAsync(deg, 0, (size_t)(2 * nN) * sizeof(int), stream);  // deg + cursor
    hist_kernel<<<sgrid, 256, 0, stream>>>(dst, deg, nE);
    scan_blksum<<<nB, 256, 0, stream>>>(deg, bsum, nN);
    scan_top<<<1, 256, 0, stream>>>(bsum, nB, rowp, nN);
    scan_final<<<nB, 256, 0, stream>>>(deg, bsum, rowp, nN);
    scatter_kernel<<<sgrid, 256, 0, stream>>>(src, dst, rowp, cursor, srcp, perm, nE);

    // ---- projections (bf16 MFMA over sorted edges, pipelined, G4 stores)
    if (single)
        proj_fused<<<pgrid, 256, 0, stream>>>(ef, We1, We2, We3, perm, G1, G2, G3, nE);
    else
        proj_single<4, 64><<<pgrid, 256, 0, stream>>>(ef, We1, 50, perm, G1, nE);

    // ================= Layer 1 (D=128 -> 50) =================
    tile_gemm<128,128, 0,0, 64, 50, 64, 16, 8, 0><<<ngrid, 256, 0, stream>>>(
        comp, 128, nullptr, 0, Wm1, bm1, P1, 64, nN);
    agg_csr<8, 64, 64><<<a8grid, 256, 0, stream>>>(G1, srcp, rowp, P1, ng, nN);
    if (!single)
        proj_single<2, 32><<<pgrid, 256, 0, stream>>>(ef, We2, 25, perm, G2, nE);
    // apply1 + P2 fused
    fused_apply_pre<128,128, 50,52, 60, 50, 52, 52, 52, 25, 32, 32, 16, 8, 8, 4>
        <<<ngrid, 256, 0, stream>>>(comp, 128, ng, 64, Wa1, ba1, Wm2, bm2, h1, P2, nN);

    // ================= Layer 2 (50 -> 25) =================
    agg_csr<4, 32, 32><<<a4grid, 256, 0, stream>>>(G2, srcp, rowp, P2, ng, nN);
    if (!single)
        proj_single<4, 64><<<pgrid, 256, 0, stream>>>(ef, We3, 64, perm, G3, nE);
    // apply2 + P3 fused
    fused_apply_pre<50,52, 25,28, 80, 25, 28, 28, 28, 64, 64, 64, 8, 4, 16, 8>
        <<<ngrid, 256, 0, stream>>>(h1, 52, ng, 64, Wa2, ba2, Wm3, bm3, h2, P3, nN);

    // ================= Layer 3: agg + apply + rowsum fused =================
    agg_apply3<<<aagrid, 256, 0, stream>>>(G3, srcp, rowp, P3, h2, Wa3, ba3, node_sum, nN);

    // ================= VM tower (folded) + scores =================
    vm_kernel<<<vgrid, 256, 0, stream>>>(vmf, W1, b1, W2, b2, vm_sum, nV);
    score_kernel<<<(nS + 255) / 256, 256, 0, stream>>>(ecmp, evm, node_sum, vm_sum, (float*)d_out, nS);
}